// Round 7
// baseline (2940.458 us; speedup 1.0000x reference)
//
#include <hip/hip_runtime.h>

// ---------------- SE3 via explicit rotation matrices (fp32, exact) ----------------
struct Q  { float w,x,y,z; };
struct V3 { float x,y,z; };
struct M3 { float m[9]; };

__device__ __forceinline__ Q qmul(Q a, Q b){
  return { a.w*b.w - a.x*b.x - a.y*b.y - a.z*b.z,
           a.w*b.x + a.x*b.w + a.y*b.z - a.z*b.y,
           a.w*b.y - a.x*b.z + a.y*b.w + a.z*b.x,
           a.w*b.z + a.x*b.y - a.y*b.x + a.z*b.w };
}
__device__ __forceinline__ Q qconj(Q q){ return { q.w, -q.x, -q.y, -q.z }; }
__device__ __forceinline__ M3 q2R(Q q){
  const float w=q.w, x=q.x, y=q.y, z=q.z;
  M3 R;
  R.m[0]=1.f-2.f*(y*y+z*z); R.m[1]=2.f*(x*y-w*z);     R.m[2]=2.f*(x*z+w*y);
  R.m[3]=2.f*(x*y+w*z);     R.m[4]=1.f-2.f*(x*x+z*z); R.m[5]=2.f*(y*z-w*x);
  R.m[6]=2.f*(x*z-w*y);     R.m[7]=2.f*(y*z+w*x);     R.m[8]=1.f-2.f*(x*x+y*y);
  return R;
}
__device__ __forceinline__ V3 mv (M3 R, V3 v){
  return { R.m[0]*v.x + R.m[1]*v.y + R.m[2]*v.z,
           R.m[3]*v.x + R.m[4]*v.y + R.m[5]*v.z,
           R.m[6]*v.x + R.m[7]*v.y + R.m[8]*v.z };
}
__device__ __forceinline__ V3 mtv(M3 R, V3 v){
  return { R.m[0]*v.x + R.m[3]*v.y + R.m[6]*v.z,
           R.m[1]*v.x + R.m[4]*v.y + R.m[7]*v.z,
           R.m[2]*v.x + R.m[5]*v.y + R.m[8]*v.z };
}

// ---------------- pure fp32 anchor kernel: no MFMA, no bf16, no workspace ----------
// block = 128 threads, tile = 8 edges. Thread c owns output column c for all 8 edges.
__global__ __launch_bounds__(128) void edge_fp32(
    const float* __restrict__ xfi, const float* __restrict__ xfj, const float* __restrict__ ef,
    const float* __restrict__ Ti,  const float* __restrict__ Tj,  const float* __restrict__ Th,
    const int*   __restrict__ batch, const float* __restrict__ u,
    const float* __restrict__ W1,  const float* __restrict__ b1,
    const float* __restrict__ W2,  const float* __restrict__ b2,
    float* __restrict__ outE, float* __restrict__ outT, int E)
{
  __shared__ float feat_s[8][520];   // feat_cat rows: [0:128)=xfi [128:256)=xfj [256:384)=ef [384:391)=T_err [391:519)=u
  __shared__ float h_s[8][130];

  const int tid = threadIdx.x;              // 0..127 = output column
  const long base = (long)blockIdx.x * 8;

  // ---- SE3 error for 8 rows (threads 0..7) + Tij_hat passthrough ----
  if (tid < 8){
    const long row = base + tid;
    const long rc  = row < E ? row : (long)(E-1);
    const float* pi = Ti + rc*7;
    const float* pj = Tj + rc*7;
    const float* ph = Th + rc*7;
    Q  qi{pi[0],pi[1],pi[2],pi[3]};  V3 tti{pi[4],pi[5],pi[6]};
    Q  qj{pj[0],pj[1],pj[2],pj[3]};  V3 ttj{pj[4],pj[5],pj[6]};
    Q  qh{ph[0],ph[1],ph[2],ph[3]};  V3 tth{ph[4],ph[5],ph[6]};
    // T_err = Th ∘ Ti ∘ inv(Tj)
    M3 Ri = q2R(qi), Rj = q2R(qj), Rh = q2R(qh);
    V3 a  = mtv(Rj, ttj);
    V3 bv = mv(Ri, a);
    V3 c  { tti.x - bv.x, tti.y - bv.y, tti.z - bv.z };
    V3 d  = mv(Rh, c);
    Q  qe = qmul(qmul(qh, qi), qconj(qj));
    feat_s[tid][384] = qe.w;
    feat_s[tid][385] = qe.x;
    feat_s[tid][386] = qe.y;
    feat_s[tid][387] = qe.z;
    feat_s[tid][388] = tth.x + d.x;
    feat_s[tid][389] = tth.y + d.y;
    feat_s[tid][390] = tth.z + d.z;
    if (row < E){
      float* o = outT + row*7;
      o[0]=ph[0]; o[1]=ph[1]; o[2]=ph[2]; o[3]=ph[3];
      o[4]=ph[4]; o[5]=ph[5]; o[6]=ph[6];
    }
  }

  // ---- stage features (coalesced; disjoint from cols 384..390) ----
  #pragma unroll
  for (int e = 0; e < 8; ++e){
    const long row = base + e;
    const long rc  = row < E ? row : (long)(E-1);
    feat_s[e][tid]       = xfi[rc*128 + tid];
    feat_s[e][128 + tid] = xfj[rc*128 + tid];
    feat_s[e][256 + tid] = ef [rc*128 + tid];
    const int ib = batch[rc];
    feat_s[e][391 + tid] = u[(size_t)ib*128 + tid];
  }
  __syncthreads();

  // ---- GEMM1 (fp32 VALU): h[e][c] = relu(b1[c] + sum_k feat[e][k] * W1[k][c]) ----
  float hacc[8];
  {
    const float bb = b1[tid];
    #pragma unroll
    for (int e = 0; e < 8; ++e) hacc[e] = bb;
  }
  #pragma unroll 4
  for (int k = 0; k < 519; ++k){
    const float w = W1[(size_t)k*128 + tid];
    #pragma unroll
    for (int e = 0; e < 8; ++e)
      hacc[e] = fmaf(feat_s[e][k], w, hacc[e]);
  }
  #pragma unroll
  for (int e = 0; e < 8; ++e)
    h_s[e][tid] = fmaxf(hacc[e], 0.f);
  __syncthreads();

  // ---- GEMM2 (fp32 VALU): out[e][c] = ef[e][c] + b2[c] + sum_cc h[e][cc] * W2[cc][c] ----
  float oacc[8];
  {
    const float bb2 = b2[tid];
    #pragma unroll
    for (int e = 0; e < 8; ++e) oacc[e] = feat_s[e][256 + tid] + bb2;
  }
  #pragma unroll 4
  for (int cc = 0; cc < 128; ++cc){
    const float w2 = W2[(size_t)cc*128 + tid];
    #pragma unroll
    for (int e = 0; e < 8; ++e)
      oacc[e] = fmaf(h_s[e][cc], w2, oacc[e]);
  }
  #pragma unroll
  for (int e = 0; e < 8; ++e){
    const long row = base + e;
    if (row < E) outE[(size_t)row*128 + tid] = oacc[e];
  }
}

extern "C" void kernel_launch(void* const* d_in, const int* in_sizes, int n_in,
                              void* d_out, int out_size, void* d_ws, size_t ws_size,
                              hipStream_t stream){
  const float* xfi  = (const float*)d_in[0];
  const float* xfj  = (const float*)d_in[1];
  const float* ef   = (const float*)d_in[2];
  const float* Ti   = (const float*)d_in[3];
  const float* Tj   = (const float*)d_in[4];
  const float* Th   = (const float*)d_in[5];
  const float* u    = (const float*)d_in[6];
  const int*   bat  = (const int*)d_in[7];
  const float* W1   = (const float*)d_in[8];
  const float* b1   = (const float*)d_in[9];
  const float* W2   = (const float*)d_in[10];
  const float* b2   = (const float*)d_in[11];
  const int E = in_sizes[0] / 128;

  float* outE = (float*)d_out;
  float* outT = outE + (size_t)E * 128;

  (void)d_ws; (void)ws_size;
  edge_fp32<<<(E + 7)/8, 128, 0, stream>>>(xfi, xfj, ef, Ti, Tj, Th, bat, u,
                                           W1, b1, W2, b2, outE, outT, E);
}

// Round 8
// 2723.136 us; speedup vs baseline: 1.0798x; 1.0798x over previous
//
#include <hip/hip_runtime.h>

typedef __attribute__((ext_vector_type(4))) float f32x4;
typedef __attribute__((ext_vector_type(8))) short bf16x8;

__device__ __forceinline__ unsigned short f2bf(float f){
  unsigned int x = __float_as_uint(f);
  return (unsigned short)((x + 0x7fffu + ((x >> 16) & 1u)) >> 16); // RNE
}

// ---------------- SE3 via explicit rotation matrices (fp32, exact) ----------------
struct Q  { float w,x,y,z; };
struct V3 { float x,y,z; };
struct M3 { float m[9]; };

__device__ __forceinline__ Q qmul(Q a, Q b){
  return { a.w*b.w - a.x*b.x - a.y*b.y - a.z*b.z,
           a.w*b.x + a.x*b.w + a.y*b.z - a.z*b.y,
           a.w*b.y - a.x*b.z + a.y*b.w + a.z*b.x,
           a.w*b.z + a.x*b.y - a.y*b.x + a.z*b.w };
}
__device__ __forceinline__ Q qconj(Q q){ return { q.w, -q.x, -q.y, -q.z }; }
__device__ __forceinline__ M3 q2R(Q q){
  const float w=q.w, x=q.x, y=q.y, z=q.z;
  M3 R;
  R.m[0]=1.f-2.f*(y*y+z*z); R.m[1]=2.f*(x*y-w*z);     R.m[2]=2.f*(x*z+w*y);
  R.m[3]=2.f*(x*y+w*z);     R.m[4]=1.f-2.f*(x*x+z*z); R.m[5]=2.f*(y*z-w*x);
  R.m[6]=2.f*(x*z-w*y);     R.m[7]=2.f*(y*z+w*x);     R.m[8]=1.f-2.f*(x*x+y*y);
  return R;
}
__device__ __forceinline__ V3 mv (M3 R, V3 v){
  return { R.m[0]*v.x + R.m[1]*v.y + R.m[2]*v.z,
           R.m[3]*v.x + R.m[4]*v.y + R.m[5]*v.z,
           R.m[6]*v.x + R.m[7]*v.y + R.m[8]*v.z };
}
__device__ __forceinline__ V3 mtv(M3 R, V3 v){
  return { R.m[0]*v.x + R.m[3]*v.y + R.m[6]*v.z,
           R.m[1]*v.x + R.m[4]*v.y + R.m[7]*v.z,
           R.m[2]*v.x + R.m[5]*v.y + R.m[8]*v.z };
}

// ---------------- anchor + MFMA-GEMM2 experiment ----------------
// block = 128 threads (2 waves), tile = 16 edges.
// GEMM1: fp32 VALU, thread c owns hidden column c for all 16 edges (16-way ILP).
// GEMM2: single 16x16x32 bf16 MFMA tile set (M=16 edges), h bf16 from LDS,
//        W2 converted in-flight (L2-hot). ONLY delta vs the green R7 anchor.
__global__ __launch_bounds__(128) void edge_k(
    const float* __restrict__ xfi, const float* __restrict__ xfj, const float* __restrict__ ef,
    const float* __restrict__ Ti,  const float* __restrict__ Tj,  const float* __restrict__ Th,
    const int*   __restrict__ batch, const float* __restrict__ u,
    const float* __restrict__ W1,  const float* __restrict__ b1,
    const float* __restrict__ W2,  const float* __restrict__ b2,
    float* __restrict__ outE, float* __restrict__ outT, int E)
{
  __shared__ float feat_s[16][520];  // [0:128)=xfi [128:256)=xfj [256:384)=ef [384:391)=T_err [391:519)=u
  __shared__ __align__(16) unsigned short hbf[16][136];   // h in bf16, padded

  const int tid = threadIdx.x;              // 0..127 = hidden/output column
  const long base = (long)blockIdx.x * 16;

  // ---- SE3 error for 16 rows (threads 0..15) + Tij_hat passthrough ----
  if (tid < 16){
    const long row = base + tid;
    const long rc  = row < E ? row : (long)(E-1);
    const float* pi = Ti + rc*7;
    const float* pj = Tj + rc*7;
    const float* ph = Th + rc*7;
    Q  qi{pi[0],pi[1],pi[2],pi[3]};  V3 tti{pi[4],pi[5],pi[6]};
    Q  qj{pj[0],pj[1],pj[2],pj[3]};  V3 ttj{pj[4],pj[5],pj[6]};
    Q  qh{ph[0],ph[1],ph[2],ph[3]};  V3 tth{ph[4],ph[5],ph[6]};
    M3 Ri = q2R(qi), Rj = q2R(qj), Rh = q2R(qh);
    V3 a  = mtv(Rj, ttj);
    V3 bv = mv(Ri, a);
    V3 c  { tti.x - bv.x, tti.y - bv.y, tti.z - bv.z };
    V3 d  = mv(Rh, c);
    Q  qe = qmul(qmul(qh, qi), qconj(qj));
    feat_s[tid][384] = qe.w;
    feat_s[tid][385] = qe.x;
    feat_s[tid][386] = qe.y;
    feat_s[tid][387] = qe.z;
    feat_s[tid][388] = tth.x + d.x;
    feat_s[tid][389] = tth.y + d.y;
    feat_s[tid][390] = tth.z + d.z;
    if (row < E){
      float* o = outT + row*7;
      o[0]=ph[0]; o[1]=ph[1]; o[2]=ph[2]; o[3]=ph[3];
      o[4]=ph[4]; o[5]=ph[5]; o[6]=ph[6];
    }
  }

  // ---- stage features (coalesced; disjoint from cols 384..390) ----
  #pragma unroll
  for (int e = 0; e < 16; ++e){
    const long row = base + e;
    const long rc  = row < E ? row : (long)(E-1);
    feat_s[e][tid]       = xfi[rc*128 + tid];
    feat_s[e][128 + tid] = xfj[rc*128 + tid];
    feat_s[e][256 + tid] = ef [rc*128 + tid];
    const int ib = batch[rc];
    feat_s[e][391 + tid] = u[(size_t)ib*128 + tid];
  }
  __syncthreads();

  // ---- GEMM1 (fp32 VALU): h[e][c] = relu(b1[c] + sum_k feat[e][k] * W1[k][c]) ----
  float hacc[16];
  {
    const float bb = b1[tid];
    #pragma unroll
    for (int e = 0; e < 16; ++e) hacc[e] = bb;
  }
  #pragma unroll 4
  for (int k = 0; k < 519; ++k){
    const float w = W1[(size_t)k*128 + tid];
    #pragma unroll
    for (int e = 0; e < 16; ++e)
      hacc[e] = fmaf(feat_s[e][k], w, hacc[e]);
  }
  #pragma unroll
  for (int e = 0; e < 16; ++e)
    hbf[e][tid] = f2bf(fmaxf(hacc[e], 0.f));
  __syncthreads();

  // ---- GEMM2 via MFMA (THE experiment) ----
  // wave wv handles cols [wv*64, wv*64+64); 4 col-fragments x 4 k-chunks.
  const int lane = tid & 63, wv = tid >> 6;
  const int l15 = lane & 15, l4 = lane >> 4;

  // acc init = ef (residual) + b2 ; C/D layout: col = l15+16*cf+64*wv, row = l4*4+r
  f32x4 acc[4];
  #pragma unroll
  for (int cf = 0; cf < 4; ++cf){
    const int col = wv*64 + cf*16 + l15;
    #pragma unroll
    for (int r = 0; r < 4; ++r){
      const int e = l4*4 + r;
      long orow = base + e; if (orow >= E) orow = E-1;
      acc[cf][r] = ef[(size_t)orow*128 + col] + b2[col];
    }
  }

  #pragma unroll
  for (int ks = 0; ks < 4; ++ks){
    const int k0 = ks*32 + l4*8;
    // A fragment: row = l15 (edge), k = k0..k0+7  (contiguous bf16x8 from LDS)
    const bf16x8 afr = *reinterpret_cast<const bf16x8*>(&hbf[l15][k0]);
    #pragma unroll
    for (int cf = 0; cf < 4; ++cf){
      const int col = wv*64 + cf*16 + l15;
      // B fragment: col = l15-part of col, k = k0..k0+7, from W2 global (L2-hot)
      union { bf16x8 v; unsigned short us[8]; } bfr;
      #pragma unroll
      for (int j = 0; j < 8; ++j)
        bfr.us[j] = f2bf(W2[(size_t)(k0 + j)*128 + col]);
      acc[cf] = __builtin_amdgcn_mfma_f32_16x16x32_bf16(afr, bfr.v, acc[cf], 0, 0, 0);
    }
  }

  // ---- store edge_feat_out ----
  #pragma unroll
  for (int cf = 0; cf < 4; ++cf){
    const int col = wv*64 + cf*16 + l15;
    #pragma unroll
    for (int r = 0; r < 4; ++r){
      const long orow = base + l4*4 + r;
      if (orow < E) outE[(size_t)orow*128 + col] = acc[cf][r];
    }
  }
}

extern "C" void kernel_launch(void* const* d_in, const int* in_sizes, int n_in,
                              void* d_out, int out_size, void* d_ws, size_t ws_size,
                              hipStream_t stream){
  const float* xfi  = (const float*)d_in[0];
  const float* xfj  = (const float*)d_in[1];
  const float* ef   = (const float*)d_in[2];
  const float* Ti   = (const float*)d_in[3];
  const float* Tj   = (const float*)d_in[4];
  const float* Th   = (const float*)d_in[5];
  const float* u    = (const float*)d_in[6];
  const int*   bat  = (const int*)d_in[7];
  const float* W1   = (const float*)d_in[8];
  const float* b1   = (const float*)d_in[9];
  const float* W2   = (const float*)d_in[10];
  const float* b2   = (const float*)d_in[11];
  const int E = in_sizes[0] / 128;

  float* outE = (float*)d_out;
  float* outT = outE + (size_t)E * 128;

  (void)d_ws; (void)ws_size;
  edge_k<<<(E + 15)/16, 128, 0, stream>>>(xfi, xfj, ef, Ti, Tj, Th, bat, u,
                                          W1, b1, W2, b2, outE, outT, E);
}

// Round 9
// 879.205 us; speedup vs baseline: 3.3445x; 3.0973x over previous
//
#include <hip/hip_runtime.h>

typedef __attribute__((ext_vector_type(4))) float f32x4;
typedef __attribute__((ext_vector_type(8))) short bf16x8;

__device__ __forceinline__ unsigned short f2bf(float f){
  unsigned int x = __float_as_uint(f);
  return (unsigned short)((x + 0x7fffu + ((x >> 16) & 1u)) >> 16); // RNE
}

// ---------------- SE3 via explicit rotation matrices (fp32, exact) ----------------
struct Q  { float w,x,y,z; };
struct V3 { float x,y,z; };
struct M3 { float m[9]; };

__device__ __forceinline__ Q qmul(Q a, Q b){
  return { a.w*b.w - a.x*b.x - a.y*b.y - a.z*b.z,
           a.w*b.x + a.x*b.w + a.y*b.z - a.z*b.y,
           a.w*b.y - a.x*b.z + a.y*b.w + a.z*b.x,
           a.w*b.z + a.x*b.y - a.y*b.x + a.z*b.w };
}
__device__ __forceinline__ Q qconj(Q q){ return { q.w, -q.x, -q.y, -q.z }; }
__device__ __forceinline__ M3 q2R(Q q){
  const float w=q.w, x=q.x, y=q.y, z=q.z;
  M3 R;
  R.m[0]=1.f-2.f*(y*y+z*z); R.m[1]=2.f*(x*y-w*z);     R.m[2]=2.f*(x*z+w*y);
  R.m[3]=2.f*(x*y+w*z);     R.m[4]=1.f-2.f*(x*x+z*z); R.m[5]=2.f*(y*z-w*x);
  R.m[6]=2.f*(x*z-w*y);     R.m[7]=2.f*(y*z+w*x);     R.m[8]=1.f-2.f*(x*x+y*y);
  return R;
}
__device__ __forceinline__ V3 mv (M3 R, V3 v){
  return { R.m[0]*v.x + R.m[1]*v.y + R.m[2]*v.z,
           R.m[3]*v.x + R.m[4]*v.y + R.m[5]*v.z,
           R.m[6]*v.x + R.m[7]*v.y + R.m[8]*v.z };
}
__device__ __forceinline__ V3 mtv(M3 R, V3 v){
  return { R.m[0]*v.x + R.m[3]*v.y + R.m[6]*v.z,
           R.m[1]*v.x + R.m[4]*v.y + R.m[7]*v.z,
           R.m[2]*v.x + R.m[5]*v.y + R.m[8]*v.z };
}

// ---------------- full-MFMA kernel (both GEMMs via proven R8 pattern) ----------
// block = 128 threads (2 waves), tile = 16 edges; wave wv owns cols [wv*64, wv*64+64).
__global__ __launch_bounds__(128) void edge_k(
    const float* __restrict__ xfi, const float* __restrict__ xfj, const float* __restrict__ ef,
    const float* __restrict__ Ti,  const float* __restrict__ Tj,  const float* __restrict__ Th,
    const int*   __restrict__ batch, const float* __restrict__ u,
    const float* __restrict__ W1,  const float* __restrict__ b1,
    const float* __restrict__ W2,  const float* __restrict__ b2,
    float* __restrict__ outE, float* __restrict__ outT, int E)
{
  // feat_cat in bf16: [0:128)=xfi [128:256)=xfj [256:384)=ef [384:391)=T_err
  //                   [391:519)=u[batch] [519:544)=zero pad. stride 552 (bank rotation).
  __shared__ __align__(16) unsigned short featb[16][552];
  __shared__ __align__(16) unsigned short hbf[16][136];

  const int tid = threadIdx.x;              // 0..127
  const long base = (long)blockIdx.x * 16;

  // ---- SE3 error for 16 rows (threads 0..15) + Tij_hat passthrough ----
  if (tid < 16){
    const long row = base + tid;
    const long rc  = row < E ? row : (long)(E-1);
    const float* pi = Ti + rc*7;
    const float* pj = Tj + rc*7;
    const float* ph = Th + rc*7;
    Q  qi{pi[0],pi[1],pi[2],pi[3]};  V3 tti{pi[4],pi[5],pi[6]};
    Q  qj{pj[0],pj[1],pj[2],pj[3]};  V3 ttj{pj[4],pj[5],pj[6]};
    Q  qh{ph[0],ph[1],ph[2],ph[3]};  V3 tth{ph[4],ph[5],ph[6]};
    M3 Ri = q2R(qi), Rj = q2R(qj), Rh = q2R(qh);
    V3 a  = mtv(Rj, ttj);
    V3 bv = mv(Ri, a);
    V3 c  { tti.x - bv.x, tti.y - bv.y, tti.z - bv.z };
    V3 d  = mv(Rh, c);
    Q  qe = qmul(qmul(qh, qi), qconj(qj));
    featb[tid][384] = f2bf(qe.w);
    featb[tid][385] = f2bf(qe.x);
    featb[tid][386] = f2bf(qe.y);
    featb[tid][387] = f2bf(qe.z);
    featb[tid][388] = f2bf(tth.x + d.x);
    featb[tid][389] = f2bf(tth.y + d.y);
    featb[tid][390] = f2bf(tth.z + d.z);
    if (row < E){
      float* o = outT + row*7;
      o[0]=ph[0]; o[1]=ph[1]; o[2]=ph[2]; o[3]=ph[3];
      o[4]=ph[4]; o[5]=ph[5]; o[6]=ph[6];
    }
  }

  // ---- stage features as bf16 (coalesced reads; disjoint LDS regions) ----
  #pragma unroll
  for (int e = 0; e < 16; ++e){
    const long row = base + e;
    const long rc  = row < E ? row : (long)(E-1);
    featb[e][tid]       = f2bf(xfi[rc*128 + tid]);
    featb[e][128 + tid] = f2bf(xfj[rc*128 + tid]);
    featb[e][256 + tid] = f2bf(ef [rc*128 + tid]);
    const int ib = batch[rc];
    featb[e][391 + tid] = f2bf(u[(size_t)ib*128 + tid]);
    if (tid < 25) featb[e][519 + tid] = 0;   // zero pad to K=544
  }
  __syncthreads();

  const int lane = tid & 63, wv = tid >> 6;
  const int l15 = lane & 15, l4 = lane >> 4;

  // ---- GEMM1 via MFMA: h[16][128], wave owns 64 cols (4 col-fragments) ----
  f32x4 acc1[4];
  #pragma unroll
  for (int cf = 0; cf < 4; ++cf){
    const int col = wv*64 + cf*16 + l15;
    const float bv = b1[col];
    #pragma unroll
    for (int r = 0; r < 4; ++r) acc1[cf][r] = bv;
  }
  #pragma unroll 4
  for (int ks = 0; ks < 17; ++ks){
    const int k0 = ks*32 + l4*8;
    // A fragment: edge row = l15, k = k0..k0+7 (contiguous bf16x8 from LDS)
    const bf16x8 afr = *reinterpret_cast<const bf16x8*>(&featb[l15][k0]);
    #pragma unroll
    for (int cf = 0; cf < 4; ++cf){
      const int col = wv*64 + cf*16 + l15;
      union { bf16x8 v; unsigned short us[8]; } bfr;
      #pragma unroll
      for (int j = 0; j < 8; ++j){
        const int kk = k0 + j;
        bfr.us[j] = (kk < 519) ? f2bf(W1[(size_t)kk*128 + col]) : (unsigned short)0;
      }
      acc1[cf] = __builtin_amdgcn_mfma_f32_16x16x32_bf16(afr, bfr.v, acc1[cf], 0, 0, 0);
    }
  }

  // h = relu -> bf16 LDS; C/D layout: col=l15(+16cf+64wv), row(edge)=l4*4+r
  #pragma unroll
  for (int cf = 0; cf < 4; ++cf){
    const int col = wv*64 + cf*16 + l15;
    #pragma unroll
    for (int r = 0; r < 4; ++r)
      hbf[l4*4 + r][col] = f2bf(fmaxf(acc1[cf][r], 0.f));
  }
  __syncthreads();

  // ---- GEMM2 via MFMA (byte-identical to green R8) ----
  f32x4 acc2[4];
  #pragma unroll
  for (int cf = 0; cf < 4; ++cf){
    const int col = wv*64 + cf*16 + l15;
    #pragma unroll
    for (int r = 0; r < 4; ++r){
      const int e = l4*4 + r;
      long orow = base + e; if (orow >= E) orow = E-1;
      acc2[cf][r] = ef[(size_t)orow*128 + col] + b2[col];
    }
  }
  #pragma unroll
  for (int ks = 0; ks < 4; ++ks){
    const int k0 = ks*32 + l4*8;
    const bf16x8 afr = *reinterpret_cast<const bf16x8*>(&hbf[l15][k0]);
    #pragma unroll
    for (int cf = 0; cf < 4; ++cf){
      const int col = wv*64 + cf*16 + l15;
      union { bf16x8 v; unsigned short us[8]; } bfr;
      #pragma unroll
      for (int j = 0; j < 8; ++j)
        bfr.us[j] = f2bf(W2[(size_t)(k0 + j)*128 + col]);
      acc2[cf] = __builtin_amdgcn_mfma_f32_16x16x32_bf16(afr, bfr.v, acc2[cf], 0, 0, 0);
    }
  }

  // ---- store edge_feat_out ----
  #pragma unroll
  for (int cf = 0; cf < 4; ++cf){
    const int col = wv*64 + cf*16 + l15;
    #pragma unroll
    for (int r = 0; r < 4; ++r){
      const long orow = base + l4*4 + r;
      if (orow < E) outE[(size_t)orow*128 + col] = acc2[cf][r];
    }
  }
}

extern "C" void kernel_launch(void* const* d_in, const int* in_sizes, int n_in,
                              void* d_out, int out_size, void* d_ws, size_t ws_size,
                              hipStream_t stream){
  const float* xfi  = (const float*)d_in[0];
  const float* xfj  = (const float*)d_in[1];
  const float* ef   = (const float*)d_in[2];
  const float* Ti   = (const float*)d_in[3];
  const float* Tj   = (const float*)d_in[4];
  const float* Th   = (const float*)d_in[5];
  const float* u    = (const float*)d_in[6];
  const int*   bat  = (const int*)d_in[7];
  const float* W1   = (const float*)d_in[8];
  const float* b1   = (const float*)d_in[9];
  const float* W2   = (const float*)d_in[10];
  const float* b2   = (const float*)d_in[11];
  const int E = in_sizes[0] / 128;

  float* outE = (float*)d_out;
  float* outT = outE + (size_t)E * 128;

  (void)d_ws; (void)ws_size;
  edge_k<<<(E + 15)/16, 128, 0, stream>>>(xfi, xfj, ef, Ti, Tj, Th, bat, u,
                                          W1, b1, W2, b2, outE, outT, E);
}

// Round 11
// 743.904 us; speedup vs baseline: 3.9527x; 1.1819x over previous
//
#include <hip/hip_runtime.h>

typedef __attribute__((ext_vector_type(4))) float f32x4;
typedef __attribute__((ext_vector_type(8))) short bf16x8;

__device__ __forceinline__ unsigned short f2bf(float f){
  unsigned int x = __float_as_uint(f);
  return (unsigned short)((x + 0x7fffu + ((x >> 16) & 1u)) >> 16); // RNE
}

// ---------------- SE3 via explicit rotation matrices (fp32, exact) ----------------
struct Q  { float w,x,y,z; };
struct V3 { float x,y,z; };
struct M3 { float m[9]; };

__device__ __forceinline__ Q qmul(Q a, Q b){
  return { a.w*b.w - a.x*b.x - a.y*b.y - a.z*b.z,
           a.w*b.x + a.x*b.w + a.y*b.z - a.z*b.y,
           a.w*b.y - a.x*b.z + a.y*b.w + a.z*b.x,
           a.w*b.z + a.x*b.y - a.y*b.x + a.z*b.w };
}
__device__ __forceinline__ Q qconj(Q q){ return { q.w, -q.x, -q.y, -q.z }; }
__device__ __forceinline__ M3 q2R(Q q){
  const float w=q.w, x=q.x, y=q.y, z=q.z;
  M3 R;
  R.m[0]=1.f-2.f*(y*y+z*z); R.m[1]=2.f*(x*y-w*z);     R.m[2]=2.f*(x*z+w*y);
  R.m[3]=2.f*(x*y+w*z);     R.m[4]=1.f-2.f*(x*x+z*z); R.m[5]=2.f*(y*z-w*x);
  R.m[6]=2.f*(x*z-w*y);     R.m[7]=2.f*(y*z+w*x);     R.m[8]=1.f-2.f*(x*x+y*y);
  return R;
}
__device__ __forceinline__ V3 mv (M3 R, V3 v){
  return { R.m[0]*v.x + R.m[1]*v.y + R.m[2]*v.z,
           R.m[3]*v.x + R.m[4]*v.y + R.m[5]*v.z,
           R.m[6]*v.x + R.m[7]*v.y + R.m[8]*v.z };
}
__device__ __forceinline__ V3 mtv(M3 R, V3 v){
  return { R.m[0]*v.x + R.m[3]*v.y + R.m[6]*v.z,
           R.m[1]*v.x + R.m[4]*v.y + R.m[7]*v.z,
           R.m[2]*v.x + R.m[5]*v.y + R.m[8]*v.z };
}

// ---------------- single kernel: 64 edges/block, 2 waves, A strictly via LDS ----
// GEMM1: features staged global->LDS-bf16 per 128-k block (R9 pattern, 4x tile);
//        tail (T_err/u/pad) in tailb LDS. B converted in-flight from fp32 W (R9).
// GEMM2: h in LDS, B in-flight (R8). No d_ws anywhere.
__global__ __launch_bounds__(128) void edge_k(
    const float* __restrict__ xfi, const float* __restrict__ xfj, const float* __restrict__ ef,
    const float* __restrict__ Ti,  const float* __restrict__ Tj,  const float* __restrict__ Th,
    const int*   __restrict__ batch, const float* __restrict__ u,
    const float* __restrict__ W1,  const float* __restrict__ b1,
    const float* __restrict__ W2,  const float* __restrict__ b2,
    float* __restrict__ outE, float* __restrict__ outT, int E)
{
  __shared__ __align__(16) unsigned short tailb[64][168]; // k=384..543: Terr|u|pad
  __shared__ __align__(16) unsigned short fbuf[64][136];  // current 128-k feature block
  __shared__ __align__(16) unsigned short hbf[64][136];   // h bf16
  __shared__ int ibat_s[64];

  const int tid = threadIdx.x;              // 0..127 (2 waves)
  const long base = (long)blockIdx.x * 64;

  // ---- Phase 1: SE3 error (threads 0..63) + Tij_hat passthrough ----
  if (tid < 64){
    const long row = base + tid;
    const long rc  = row < E ? row : (long)(E-1);
    const float* pi = Ti + rc*7;
    const float* pj = Tj + rc*7;
    const float* ph = Th + rc*7;
    Q  qi{pi[0],pi[1],pi[2],pi[3]};  V3 tti{pi[4],pi[5],pi[6]};
    Q  qj{pj[0],pj[1],pj[2],pj[3]};  V3 ttj{pj[4],pj[5],pj[6]};
    Q  qh{ph[0],ph[1],ph[2],ph[3]};  V3 tth{ph[4],ph[5],ph[6]};
    M3 Ri = q2R(qi), Rj = q2R(qj), Rh = q2R(qh);
    V3 a  = mtv(Rj, ttj);
    V3 bv = mv(Ri, a);
    V3 c  { tti.x - bv.x, tti.y - bv.y, tti.z - bv.z };
    V3 d  = mv(Rh, c);
    Q  qe = qmul(qmul(qh, qi), qconj(qj));
    tailb[tid][0] = f2bf(qe.w);
    tailb[tid][1] = f2bf(qe.x);
    tailb[tid][2] = f2bf(qe.y);
    tailb[tid][3] = f2bf(qe.z);
    tailb[tid][4] = f2bf(tth.x + d.x);
    tailb[tid][5] = f2bf(tth.y + d.y);
    tailb[tid][6] = f2bf(tth.z + d.z);
    ibat_s[tid] = batch[rc];
    if (row < E){
      float* o = outT + row*7;
      o[0]=ph[0]; o[1]=ph[1]; o[2]=ph[2]; o[3]=ph[3];
      o[4]=ph[4]; o[5]=ph[5]; o[6]=ph[6];
    }
  }
  __syncthreads();

  // ---- stage u rows + zero pad into tail block (cols 7..134 = u, 135..159 = 0) ----
  for (int e = 0; e < 64; ++e){
    const int ib = ibat_s[e];
    tailb[e][7 + tid] = f2bf(u[(size_t)ib*128 + tid]);
    if (tid < 25) tailb[e][135 + tid] = 0;
  }

  const int lane = tid & 63, wv = tid >> 6;
  const int l15 = lane & 15, l4 = lane >> 4;

  // ---- GEMM1: acc1[a][cf]; wave owns cols [wv*64, wv*64+64) ----
  f32x4 acc1[4][4];
  #pragma unroll
  for (int cf = 0; cf < 4; ++cf){
    const int col = wv*64 + cf*16 + l15;
    const float bv = b1[col];
    #pragma unroll
    for (int a = 0; a < 4; ++a){
      #pragma unroll
      for (int r = 0; r < 4; ++r) acc1[a][cf][r] = bv;
    }
  }

  const float* fps[3] = { xfi, xfj, ef };
  // feature blocks fb = 0..2: stage 64x128 bf16 to LDS, then 4 k-chunks of MFMA
  for (int fb = 0; fb < 3; ++fb){
    const float* F = fps[fb];
    __syncthreads();   // previous consumers done before overwrite (also covers tailb stage)
    for (int idx = tid; idx < 64*128; idx += 128){
      const int e = idx >> 7, c = idx & 127;
      long rr = base + e; if (rr >= E) rr = E-1;
      fbuf[e][c] = f2bf(F[(size_t)rr*128 + c]);
    }
    __syncthreads();
    #pragma unroll
    for (int kc = 0; kc < 4; ++kc){
      const int kl = kc*32 + l4*8;          // k within this 128-block
      bf16x8 afr[4];
      #pragma unroll
      for (int a = 0; a < 4; ++a)
        afr[a] = *reinterpret_cast<const bf16x8*>(&fbuf[a*16 + l15][kl]);
      #pragma unroll
      for (int cf = 0; cf < 4; ++cf){
        const int col = wv*64 + cf*16 + l15;
        union { bf16x8 v; unsigned short us[8]; } B;
        #pragma unroll
        for (int j = 0; j < 8; ++j){
          const int kk = fb*128 + kl + j;
          B.us[j] = f2bf(W1[(size_t)kk*128 + col]);
        }
        #pragma unroll
        for (int a = 0; a < 4; ++a)
          acc1[a][cf] = __builtin_amdgcn_mfma_f32_16x16x32_bf16(afr[a], B.v, acc1[a][cf], 0, 0, 0);
      }
    }
  }
  // tail k-chunks (k = 384..543) from tailb
  #pragma unroll
  for (int tc = 0; tc < 5; ++tc){
    const int kt = tc*32 + l4*8;
    bf16x8 afr[4];
    #pragma unroll
    for (int a = 0; a < 4; ++a)
      afr[a] = *reinterpret_cast<const bf16x8*>(&tailb[a*16 + l15][kt]);
    #pragma unroll
    for (int cf = 0; cf < 4; ++cf){
      const int col = wv*64 + cf*16 + l15;
      union { bf16x8 v; unsigned short us[8]; } B;
      #pragma unroll
      for (int j = 0; j < 8; ++j){
        const int kk = 384 + kt + j;
        B.us[j] = (kk < 519) ? f2bf(W1[(size_t)kk*128 + col]) : (unsigned short)0;
      }
      #pragma unroll
      for (int a = 0; a < 4; ++a)
        acc1[a][cf] = __builtin_amdgcn_mfma_f32_16x16x32_bf16(afr[a], B.v, acc1[a][cf], 0, 0, 0);
    }
  }

  // ---- h = relu -> bf16 LDS; C/D: col=l15(+16cf+64wv), edge row=a*16+l4*4+r ----
  #pragma unroll
  for (int a = 0; a < 4; ++a){
    #pragma unroll
    for (int cf = 0; cf < 4; ++cf){
      const int col = wv*64 + cf*16 + l15;
      #pragma unroll
      for (int r = 0; r < 4; ++r)
        hbf[a*16 + l4*4 + r][col] = f2bf(fmaxf(acc1[a][cf][r], 0.f));
    }
  }
  __syncthreads();

  // ---- GEMM2: += h @ W2, B in-flight (R8-proven) ----
  f32x4 acc2[4][4];
  #pragma unroll
  for (int cf = 0; cf < 4; ++cf){
    const int col = wv*64 + cf*16 + l15;
    const float bv2 = b2[col];
    #pragma unroll
    for (int a = 0; a < 4; ++a){
      #pragma unroll
      for (int r = 0; r < 4; ++r){
        long orow = base + a*16 + l4*4 + r;
        if (orow >= E) orow = E-1;
        acc2[a][cf][r] = ef[(size_t)orow*128 + col] + bv2;
      }
    }
  }
  #pragma unroll
  for (int ks = 0; ks < 4; ++ks){
    const int k0 = ks*32 + l4*8;
    bf16x8 afr[4];
    #pragma unroll
    for (int a = 0; a < 4; ++a)
      afr[a] = *reinterpret_cast<const bf16x8*>(&hbf[a*16 + l15][k0]);
    #pragma unroll
    for (int cf = 0; cf < 4; ++cf){
      const int col = wv*64 + cf*16 + l15;
      union { bf16x8 v; unsigned short us[8]; } B;
      #pragma unroll
      for (int j = 0; j < 8; ++j)
        B.us[j] = f2bf(W2[(size_t)(k0 + j)*128 + col]);
      #pragma unroll
      for (int a = 0; a < 4; ++a)
        acc2[a][cf] = __builtin_amdgcn_mfma_f32_16x16x32_bf16(afr[a], B.v, acc2[a][cf], 0, 0, 0);
    }
  }

  // ---- store edge_feat_out ----
  #pragma unroll
  for (int a = 0; a < 4; ++a){
    #pragma unroll
    for (int cf = 0; cf < 4; ++cf){
      const int col = wv*64 + cf*16 + l15;
      #pragma unroll
      for (int r = 0; r < 4; ++r){
        const long orow = base + a*16 + l4*4 + r;
        if (orow < E) outE[(size_t)orow*128 + col] = acc2[a][cf][r];
      }
    }
  }
}

extern "C" void kernel_launch(void* const* d_in, const int* in_sizes, int n_in,
                              void* d_out, int out_size, void* d_ws, size_t ws_size,
                              hipStream_t stream){
  const float* xfi  = (const float*)d_in[0];
  const float* xfj  = (const float*)d_in[1];
  const float* ef   = (const float*)d_in[2];
  const float* Ti   = (const float*)d_in[3];
  const float* Tj   = (const float*)d_in[4];
  const float* Th   = (const float*)d_in[5];
  const float* u    = (const float*)d_in[6];
  const int*   bat  = (const int*)d_in[7];
  const float* W1   = (const float*)d_in[8];
  const float* b1   = (const float*)d_in[9];
  const float* W2   = (const float*)d_in[10];
  const float* b2   = (const float*)d_in[11];
  const int E = in_sizes[0] / 128;

  float* outE = (float*)d_out;
  float* outT = outE + (size_t)E * 128;

  (void)d_ws; (void)ws_size;
  edge_k<<<(E + 63)/64, 128, 0, stream>>>(xfi, xfj, ef, Ti, Tj, Th, bat, u,
                                          W1, b1, W2, b2, outE, outT, E);
}